// Round 10
// baseline (150.588 us; speedup 1.0000x reference)
//
#include <hip/hip_runtime.h>
#include <math.h>

#define TT 16384   // B*S tokens
#define HH 4096    // hidden
#define EE 64      // experts
#define KK 8       // top-k
#define TB 16      // tokens per block
#define NCH 64     // K chunks of 64
#define SEGC 4     // chunks per segment (256 k)
#define NSEG (NCH / SEGC)
#define NPL 3      // digit planes (3-digit signed-byte decomposition)

typedef int v4i __attribute__((ext_vector_type(4)));

// 3-digit signed-byte decomposition (measured-safe precision floor):
//   x: |x| < 8    -> X = rn(x*2^20), |X| < 2^23
//   w: |w| < 0.12 -> W = rn(w*2^26), |W| < 2^23
// logit = 2^-46 * sum_s 256^s * P_s,  P_s = sum_{i+j=s} <X_i, W_j>
// Keep classes s>=1 (drop (0,0), ~5e-9): 8 MFMAs, 4 acc classes.
// round-2 post-mortem: 2-plane x (2^12) -> ~4.5e-5 logit err -> top-8 flips.
#define SXF 1048576.0f     // 2^20
#define SWF 67108864.0f    // 2^26

__device__ __forceinline__ unsigned ytrans(float v, float scale) {
  int X = __float2int_rn(v * scale);
  return (unsigned)X + 0x80808080u;
}

__device__ __forceinline__ unsigned planeword(unsigned y0, unsigned y1,
                                              unsigned y2, unsigned y3, int p) {
  unsigned sel = (unsigned)p | (((unsigned)p + 4u) << 4);
  unsigned t01 = __byte_perm(y0, y1, sel);
  unsigned t23 = __byte_perm(y2, y3, sel);
  return __byte_perm(t01, t23, 0x5410u) ^ 0x80808080u;
}

// 16 consecutive f32 -> 3 int8-digit plane fragments (v4i each).
__device__ __forceinline__ void decomp16(const float4 (&f)[4], float scale,
                                         v4i (&A)[NPL]) {
  unsigned y[16];
#pragma unroll
  for (int q = 0; q < 4; ++q) {
    y[4 * q + 0] = ytrans(f[q].x, scale);
    y[4 * q + 1] = ytrans(f[q].y, scale);
    y[4 * q + 2] = ytrans(f[q].z, scale);
    y[4 * q + 3] = ytrans(f[q].w, scale);
  }
#pragma unroll
  for (int p = 0; p < NPL; ++p)
#pragma unroll
    for (int q = 0; q < 4; ++q)
      A[p][q] =
          (int)planeword(y[4 * q], y[4 * q + 1], y[4 * q + 2], y[4 * q + 3], p);
}

// w -> fragment-ordered digit planes: wgs[c][p<3][kg4][e] (16B units).
__global__ void wdecomp_kernel(const float* __restrict__ w,
                               char* __restrict__ wgs) {
  int t = blockIdx.x * 256 + threadIdx.x;   // 16384 threads
  int kg4 = t & 3, c = (t >> 2) & 63, e = t >> 8;
  const float* src = w + (size_t)e * HH + c * 64 + kg4 * 16;
  float4 f[4];
#pragma unroll
  for (int q = 0; q < 4; ++q) f[q] = *(const float4*)(src + 4 * q);
  v4i P[NPL];
  decomp16(f, SWF, P);
#pragma unroll
  for (int p = 0; p < NPL; ++p)
    *(v4i*)(wgs + ((((size_t)c * NPL + p) * 4 + kg4) * 64 + e) * 16) = P[p];
}

// Main: r8 champion with ONE change — fbuf register-double-buffered so
// LOADR(seg+2) is issued a FULL SEGMENT before DECOMPW(seg+2) consumes it
// (r8 issued LOADR(seg+1) and consumed it the same iteration: slack ~= the
// MFMA phase < congested HBM latency -> every wave stalled at DECOMPW).
// Manual 2x unroll with NAMED buffers fbA/fbB (rule-20 safe).
template <bool USEWG>
__global__ __launch_bounds__(256, 4)
void router_kernel(const float* __restrict__ x, const float* __restrict__ w,
                   const float* __restrict__ bias, const char* __restrict__ wgs,
                   float* __restrict__ out_full, float* __restrict__ out_idx) {
  __shared__ union {
    char xs[2][NPL][TB][256];    // [buf][plane][tok][k-byte], 12 KB per buf
    double lgp[TB][EE + 2];      // epilogue logits
  } sm;

  const int tid  = threadIdx.x;  // 0..255
  const int tok0 = blockIdx.x * TB;
  const int lane = tid & 63;
  const int wid  = tid >> 6;     // 0..3
  const int eq   = wid;          // expert quarter (16 experts)
  const int col  = lane & 15;    // A token row / B expert col
  const int kg4  = lane >> 4;    // k-group: 16 k elements
  const int skq  = tid & 63;     // staging k-quad within segment row

  v4i acc[4];
#pragma unroll
  for (int s = 0; s < 4; ++s)
#pragma unroll
    for (int q = 0; q < 4; ++q) acc[s][q] = 0;

  float4 fbA[4], fbB[4];         // x prefetch, 2 segments deep

  auto LOADR = [&](int segi, float4 (&f)[4]) {
#pragma unroll
    for (int j = 0; j < 4; ++j) {
      int stok = j * 4 + wid;
      f[j] = *(const float4*)(x + (size_t)(tok0 + stok) * HH + segi * 256 +
                              skq * 4);
    }
  };

  auto DECOMPW = [&](int buf, const float4 (&f)[4]) {
#pragma unroll
    for (int j = 0; j < 4; ++j) {
      int stok = j * 4 + wid;
      int ksl = skq >> 2, kin = skq & 3;
      unsigned y0 = ytrans(f[j].x, SXF), y1 = ytrans(f[j].y, SXF),
               y2 = ytrans(f[j].z, SXF), y3 = ytrans(f[j].w, SXF);
#pragma unroll
      for (int p = 0; p < NPL; ++p) {
        unsigned d = planeword(y0, y1, y2, y3, p);
        *(unsigned*)(&sm.xs[buf][p][stok][((ksl ^ stok) << 4) + kin * 4]) = d;
      }
    }
  };

  auto AREAD = [&](int buf, int cc, v4i (&A)[NPL]) {
    int sl = (cc * 4 + kg4) ^ col;
#pragma unroll
    for (int p = 0; p < NPL; ++p)
      A[p] = *(const v4i*)(&sm.xs[buf][p][col][sl << 4]);
  };

  auto BLOAD = [&](int c, v4i (&B)[NPL]) {
    if (c >= NCH) return;
    if (USEWG) {
#pragma unroll
      for (int p = 0; p < NPL; ++p)
        B[p] = *(const v4i*)(wgs +
                             ((((size_t)c * NPL + p) * 4 + kg4) * 64 +
                              eq * 16 + col) * 16);
    } else {
      float4 wf[4];
#pragma unroll
      for (int q = 0; q < 4; ++q)
        wf[q] = *(const float4*)(w + (size_t)(eq * 16 + col) * HH + c * 64 +
                                 kg4 * 16 + 4 * q);
      decomp16(wf, SWF, B);
    }
  };

  v4i A0[NPL], A1[NPL], B0[NPL], B1[NPL], B2[NPL];
#pragma unroll
  for (int p = 0; p < NPL; ++p) { B2[p] = v4i{0, 0, 0, 0}; B1[p] = B2[p]; }
#pragma unroll
  for (int p = 0; p < NPL; ++p) A1[p] = v4i{0, 0, 0, 0};

  // Per-segment body. fbCur holds x of segment seg+1 (loaded one iteration
  // ago); fbNext receives x of segment seg+2 (consumed next iteration).
  auto SEGBODY = [&](int seg, const float4 (&fbCur)[4], float4 (&fbNext)[4]) {
    const int buf = seg & 1;
    if (seg + 2 < NSEG) LOADR(seg + 2, fbNext);   // full-segment slack
#pragma unroll
    for (int cc = 0; cc < SEGC; ++cc) {
      const int c = seg * SEGC + cc;
      BLOAD(c + 2, B2);                   // 2-chunk-deep B prefetch (L2)
      if (cc + 1 < SEGC) AREAD(buf, cc + 1, A1);
      // 8 digit-pair MFMAs on current fragments (classes s=i+j>=1)
#pragma unroll
      for (int i = 0; i < NPL; ++i)
#pragma unroll
        for (int j2 = 0; j2 < NPL; ++j2)
          if (i + j2 >= 1)
            acc[i + j2 - 1] = __builtin_amdgcn_mfma_i32_16x16x64_i8(
                A0[i], B0[j2], acc[i + j2 - 1], 0, 0, 0);
      if (cc + 1 < SEGC) {
#pragma unroll
        for (int p = 0; p < NPL; ++p) A0[p] = A1[p];
      }
#pragma unroll
      for (int p = 0; p < NPL; ++p) { B0[p] = B1[p]; B1[p] = B2[p]; }
    }
    if (seg + 1 < NSEG) DECOMPW(buf ^ 1, fbCur);
    __syncthreads();
    if (seg + 1 < NSEG) AREAD(buf ^ 1, 0, A0);   // chunk-0 A of next segment
  };

  LOADR(0, fbA);
  DECOMPW(0, fbA);          // one unavoidable cold stall
  LOADR(1, fbA);            // refill fbA: seg-1 data for iteration 0
  __syncthreads();
  AREAD(0, 0, A0);
  BLOAD(0, B0);
  BLOAD(1, B1);

  for (int s2 = 0; s2 < NSEG; s2 += 2) {   // manual 2x, named buffers
    SEGBODY(s2, fbA, fbB);
    SEGBODY(s2 + 1, fbB, fbA);
  }

  // ---- combine classes in fp64 (EXACT: ints x powers of 2, < 2^53) ----
  const double sc[4] = {0x1p-38, 0x1p-30, 0x1p-22, 0x1p-14};
#pragma unroll
  for (int r = 0; r < 4; ++r) {
    int tkr = (lane >> 4) * 4 + r;   // C/D row map (16x16 family, validated)
    double v = 0.0;
#pragma unroll
    for (int s = 0; s < 4; ++s) v += (double)acc[s][r] * sc[s];
    sm.lgp[tkr][eq * 16 + col] = v;
  }
  __syncthreads();

  // ---- epilogue v2 (r8): u64-key exact top-8, 2 tokens/wave in parallel ----
  {
    const int h = lane >> 5;   // token slot within pass (half-wave)
    const int l = lane & 31;   // expert lane: owns experts l and l+32
#pragma unroll
    for (int p = 0; p < 2; ++p) {
      const int t = wid * 4 + p * 2 + h;
      double v0 = sm.lgp[t][l] + (double)bias[l];
      double v1 = sm.lgp[t][l + 32] + (double)bias[l + 32];
      long long b0 = __double_as_longlong(v0);
      long long b1 = __double_as_longlong(v1);
      unsigned long long k0 =
          (((unsigned long long)(b0 ^ (b0 < 0 ? -1ll
                                             : (long long)0x8000000000000000ll))) &
           ~63ull) | (unsigned long long)(63 - l);
      unsigned long long k1 =
          (((unsigned long long)(b1 ^ (b1 < 0 ? -1ll
                                             : (long long)0x8000000000000000ll))) &
           ~63ull) | (unsigned long long)(63 - (l + 32));

      // max logit key (width-32 reduce)
      unsigned long long km = k0 > k1 ? k0 : k1;
#pragma unroll
      for (int off = 16; off >= 1; off >>= 1) {
        unsigned long long o = __shfl_xor(km, off, 32);
        km = o > km ? o : km;
      }
      long long mb = (long long)((km & 0x8000000000000000ull)
                                     ? (km ^ 0x8000000000000000ull)
                                     : ~km);
      double vmax = __longlong_as_double(mb);

      float ex0 = __expf((float)(v0 - vmax));
      float ex1 = __expf((float)(v1 - vmax));
      float ss = ex0 + ex1;
#pragma unroll
      for (int off = 16; off >= 1; off >>= 1) ss += __shfl_xor(ss, off, 32);
      float sc0 = ex0 / ss, sc1 = ex1 / ss;

      unsigned long long c0 = k0, c1 = k1;
      float o0 = 0.0f, o1 = 0.0f;
      const size_t tg = (size_t)(tok0 + t);
#pragma unroll
      for (int k = 0; k < KK; ++k) {
        unsigned long long bk = c0 > c1 ? c0 : c1;
#pragma unroll
        for (int off = 16; off >= 1; off >>= 1) {
          unsigned long long o = __shfl_xor(bk, off, 32);
          bk = o > bk ? o : bk;
        }
        int be = 63 - (int)(bk & 63ull);
        if (l == k) out_idx[tg * KK + k] = (float)be;
        if (be == l)      { o0 = sc0; c0 = 0ull; }
        if (be == l + 32) { o1 = sc1; c1 = 0ull; }
      }
      out_full[tg * EE + l]      = o0;
      out_full[tg * EE + l + 32] = o1;
    }
  }
}

extern "C" void kernel_launch(void* const* d_in, const int* in_sizes, int n_in,
                              void* d_out, int out_size, void* d_ws, size_t ws_size,
                              hipStream_t stream) {
  const float* x = (const float*)d_in[0];
  const float* w = (const float*)d_in[1];
  const float* b = (const float*)d_in[2];
  float* out_full = (float*)d_out;                 // [T, E] scattered scores
  float* out_idx  = out_full + (size_t)TT * EE;    // [T, K] indices as f32
  if (d_ws && ws_size >= (size_t)(EE * HH * NPL)) {
    char* wgs = (char*)d_ws;
    wdecomp_kernel<<<64, 256, 0, stream>>>(w, wgs);
    router_kernel<true><<<TT / TB, 256, 0, stream>>>(x, w, b, wgs, out_full,
                                                     out_idx);
  } else {
    router_kernel<false><<<TT / TB, 256, 0, stream>>>(x, w, b, nullptr,
                                                      out_full, out_idx);
  }
}

// Round 11
// 79.280 us; speedup vs baseline: 1.8995x; 1.8995x over previous
//
#include <hip/hip_runtime.h>
#include <math.h>

#define TT 16384   // B*S tokens
#define HH 4096    // hidden
#define EE 64      // experts
#define KK 8       // top-k
#define TB 16      // tokens per block
#define NCH 64     // K chunks of 64
#define SEGC 4     // chunks per segment (256 k)
#define NSEG (NCH / SEGC)
#define NPL 3      // digit planes (3-digit signed-byte decomposition)

typedef int v4i __attribute__((ext_vector_type(4)));

// 3-digit signed-byte decomposition (measured-safe precision floor):
//   x: |x| < 8    -> X = rn(x*2^20), |X| < 2^23
//   w: |w| < 0.12 -> W = rn(w*2^26), |W| < 2^23
// logit = 2^-46 * sum_s 256^s * P_s,  P_s = sum_{i+j=s} <X_i, W_j>
// Keep classes s>=1 (drop (0,0), ~5e-9): 8 MFMAs, 4 acc classes.
// round-2 post-mortem: 2-plane x (2^12) -> ~4.5e-5 logit err -> top-8 flips.
#define SXF 1048576.0f     // 2^20
#define SWF 67108864.0f    // 2^26

__device__ __forceinline__ unsigned ytrans(float v, float scale) {
  int X = __float2int_rn(v * scale);
  return (unsigned)X + 0x80808080u;
}

__device__ __forceinline__ unsigned planeword(unsigned y0, unsigned y1,
                                              unsigned y2, unsigned y3, int p) {
  unsigned sel = (unsigned)p | (((unsigned)p + 4u) << 4);
  unsigned t01 = __byte_perm(y0, y1, sel);
  unsigned t23 = __byte_perm(y2, y3, sel);
  return __byte_perm(t01, t23, 0x5410u) ^ 0x80808080u;
}

// 16 consecutive f32 -> 3 int8-digit plane fragments (v4i each).
__device__ __forceinline__ void decomp16(const float4 (&f)[4], float scale,
                                         v4i (&A)[NPL]) {
  unsigned y[16];
#pragma unroll
  for (int q = 0; q < 4; ++q) {
    y[4 * q + 0] = ytrans(f[q].x, scale);
    y[4 * q + 1] = ytrans(f[q].y, scale);
    y[4 * q + 2] = ytrans(f[q].z, scale);
    y[4 * q + 3] = ytrans(f[q].w, scale);
  }
#pragma unroll
  for (int p = 0; p < NPL; ++p)
#pragma unroll
    for (int q = 0; q < 4; ++q)
      A[p][q] =
          (int)planeword(y[4 * q], y[4 * q + 1], y[4 * q + 2], y[4 * q + 3], p);
}

// w -> fragment-ordered digit planes: wgs[c][p<3][kg4][e] (16B units).
__global__ void wdecomp_kernel(const float* __restrict__ w,
                               char* __restrict__ wgs) {
  int t = blockIdx.x * 256 + threadIdx.x;   // 16384 threads
  int kg4 = t & 3, c = (t >> 2) & 63, e = t >> 8;
  const float* src = w + (size_t)e * HH + c * 64 + kg4 * 16;
  float4 f[4];
#pragma unroll
  for (int q = 0; q < 4; ++q) f[q] = *(const float4*)(src + 4 * q);
  v4i P[NPL];
  decomp16(f, SWF, P);
#pragma unroll
  for (int p = 0; p < NPL; ++p)
    *(v4i*)(wgs + ((((size_t)c * NPL + p) * 4 + kg4) * 64 + e) * 16) = P[p];
}

// Main: r8 champion (81.2us) + ONE line: sched_barrier(0) right after LOADR
// pins the 4 global_load_dwordx4 at the segment top (the compiler was
// sinking them to just before DECOMPW -> zero prefetch distance; r8's
// VGPR=56 proves the fbuf live range was collapsed). One buffer only:
// 56+64 live regs fits the 128-VGPR cap of launch_bounds(256,4), unlike
// r10's two-buffer attempt which spilled (FETCH 135->291 MB).
template <bool USEWG>
__global__ __launch_bounds__(256, 4)
void router_kernel(const float* __restrict__ x, const float* __restrict__ w,
                   const float* __restrict__ bias, const char* __restrict__ wgs,
                   float* __restrict__ out_full, float* __restrict__ out_idx) {
  __shared__ union {
    char xs[2][NPL][TB][256];    // [buf][plane][tok][k-byte], 12 KB per buf
    double lgp[TB][EE + 2];      // epilogue logits
  } sm;

  const int tid  = threadIdx.x;  // 0..255
  const int tok0 = blockIdx.x * TB;
  const int lane = tid & 63;
  const int wid  = tid >> 6;     // 0..3
  const int eq   = wid;          // expert quarter (16 experts)
  const int col  = lane & 15;    // A token row / B expert col
  const int kg4  = lane >> 4;    // k-group: 16 k elements
  const int skq  = tid & 63;     // staging k-quad within segment row

  v4i acc[4];
#pragma unroll
  for (int s = 0; s < 4; ++s)
#pragma unroll
    for (int q = 0; q < 4; ++q) acc[s][q] = 0;

  float4 fbuf[4];

  auto LOADR = [&](int segi) {
#pragma unroll
    for (int j = 0; j < 4; ++j) {
      int stok = j * 4 + wid;
      fbuf[j] = *(const float4*)(x + (size_t)(tok0 + stok) * HH + segi * 256 +
                                 skq * 4);
    }
  };

  auto DECOMPW = [&](int buf) {
#pragma unroll
    for (int j = 0; j < 4; ++j) {
      int stok = j * 4 + wid;
      int ksl = skq >> 2, kin = skq & 3;
      unsigned y0 = ytrans(fbuf[j].x, SXF), y1 = ytrans(fbuf[j].y, SXF),
               y2 = ytrans(fbuf[j].z, SXF), y3 = ytrans(fbuf[j].w, SXF);
#pragma unroll
      for (int p = 0; p < NPL; ++p) {
        unsigned d = planeword(y0, y1, y2, y3, p);
        *(unsigned*)(&sm.xs[buf][p][stok][((ksl ^ stok) << 4) + kin * 4]) = d;
      }
    }
  };

  auto AREAD = [&](int buf, int cc, v4i (&A)[NPL]) {
    int sl = (cc * 4 + kg4) ^ col;
#pragma unroll
    for (int p = 0; p < NPL; ++p)
      A[p] = *(const v4i*)(&sm.xs[buf][p][col][sl << 4]);
  };

  auto BLOAD = [&](int c, v4i (&B)[NPL]) {
    if (c >= NCH) return;
    if (USEWG) {
#pragma unroll
      for (int p = 0; p < NPL; ++p)
        B[p] = *(const v4i*)(wgs +
                             ((((size_t)c * NPL + p) * 4 + kg4) * 64 +
                              eq * 16 + col) * 16);
    } else {
      float4 wf[4];
#pragma unroll
      for (int q = 0; q < 4; ++q)
        wf[q] = *(const float4*)(w + (size_t)(eq * 16 + col) * HH + c * 64 +
                                 kg4 * 16 + 4 * q);
      decomp16(wf, SWF, B);
    }
  };

  v4i A0[NPL], A1[NPL], B0[NPL], B1[NPL], B2[NPL];
#pragma unroll
  for (int p = 0; p < NPL; ++p) { B2[p] = v4i{0, 0, 0, 0}; B1[p] = B2[p]; }
#pragma unroll
  for (int p = 0; p < NPL; ++p) A1[p] = v4i{0, 0, 0, 0};

  LOADR(0);
  DECOMPW(0);
  __syncthreads();
  AREAD(0, 0, A0);
  BLOAD(0, B0);
  BLOAD(1, B1);

#pragma unroll 2
  for (int seg = 0; seg < NSEG; ++seg) {
    const int buf = seg & 1;
    if (seg + 1 < NSEG) {
      LOADR(seg + 1);                     // HBM issue early (T14)
      __builtin_amdgcn_sched_barrier(0);  // PIN: forbid sinking these loads
    }
#pragma unroll
    for (int cc = 0; cc < SEGC; ++cc) {
      const int c = seg * SEGC + cc;
      BLOAD(c + 2, B2);                   // 2-chunk-deep B prefetch (L2)
      if (cc + 1 < SEGC) AREAD(buf, cc + 1, A1);
      // 8 digit-pair MFMAs on current fragments (classes s=i+j>=1)
#pragma unroll
      for (int i = 0; i < NPL; ++i)
#pragma unroll
        for (int j2 = 0; j2 < NPL; ++j2)
          if (i + j2 >= 1)
            acc[i + j2 - 1] = __builtin_amdgcn_mfma_i32_16x16x64_i8(
                A0[i], B0[j2], acc[i + j2 - 1], 0, 0, 0);
      if (cc + 1 < SEGC) {
#pragma unroll
        for (int p = 0; p < NPL; ++p) A0[p] = A1[p];
      }
#pragma unroll
      for (int p = 0; p < NPL; ++p) { B0[p] = B1[p]; B1[p] = B2[p]; }
    }
    if (seg + 1 < NSEG) DECOMPW(buf ^ 1);
    __syncthreads();
    if (seg + 1 < NSEG) AREAD(buf ^ 1, 0, A0);   // chunk-0 A of next segment
  }

  // ---- combine classes in fp64 (EXACT: ints x powers of 2, < 2^53) ----
  const double sc[4] = {0x1p-38, 0x1p-30, 0x1p-22, 0x1p-14};
#pragma unroll
  for (int r = 0; r < 4; ++r) {
    int tkr = (lane >> 4) * 4 + r;   // C/D row map (16x16 family, validated)
    double v = 0.0;
#pragma unroll
    for (int s = 0; s < 4; ++s) v += (double)acc[s][r] * sc[s];
    sm.lgp[tkr][eq * 16 + col] = v;
  }
  __syncthreads();

  // ---- epilogue v2 (r8): u64-key exact top-8, 2 tokens/wave in parallel ----
  {
    const int h = lane >> 5;   // token slot within pass (half-wave)
    const int l = lane & 31;   // expert lane: owns experts l and l+32
#pragma unroll
    for (int p = 0; p < 2; ++p) {
      const int t = wid * 4 + p * 2 + h;
      double v0 = sm.lgp[t][l] + (double)bias[l];
      double v1 = sm.lgp[t][l + 32] + (double)bias[l + 32];
      long long b0 = __double_as_longlong(v0);
      long long b1 = __double_as_longlong(v1);
      unsigned long long k0 =
          (((unsigned long long)(b0 ^ (b0 < 0 ? -1ll
                                             : (long long)0x8000000000000000ll))) &
           ~63ull) | (unsigned long long)(63 - l);
      unsigned long long k1 =
          (((unsigned long long)(b1 ^ (b1 < 0 ? -1ll
                                             : (long long)0x8000000000000000ll))) &
           ~63ull) | (unsigned long long)(63 - (l + 32));

      // max logit key (width-32 reduce)
      unsigned long long km = k0 > k1 ? k0 : k1;
#pragma unroll
      for (int off = 16; off >= 1; off >>= 1) {
        unsigned long long o = __shfl_xor(km, off, 32);
        km = o > km ? o : km;
      }
      long long mb = (long long)((km & 0x8000000000000000ull)
                                     ? (km ^ 0x8000000000000000ull)
                                     : ~km);
      double vmax = __longlong_as_double(mb);

      float ex0 = __expf((float)(v0 - vmax));
      float ex1 = __expf((float)(v1 - vmax));
      float ss = ex0 + ex1;
#pragma unroll
      for (int off = 16; off >= 1; off >>= 1) ss += __shfl_xor(ss, off, 32);
      float sc0 = ex0 / ss, sc1 = ex1 / ss;

      unsigned long long c0 = k0, c1 = k1;
      float o0 = 0.0f, o1 = 0.0f;
      const size_t tg = (size_t)(tok0 + t);
#pragma unroll
      for (int k = 0; k < KK; ++k) {
        unsigned long long bk = c0 > c1 ? c0 : c1;
#pragma unroll
        for (int off = 16; off >= 1; off >>= 1) {
          unsigned long long o = __shfl_xor(bk, off, 32);
          bk = o > bk ? o : bk;
        }
        int be = 63 - (int)(bk & 63ull);
        if (l == k) out_idx[tg * KK + k] = (float)be;
        if (be == l)      { o0 = sc0; c0 = 0ull; }
        if (be == l + 32) { o1 = sc1; c1 = 0ull; }
      }
      out_full[tg * EE + l]      = o0;
      out_full[tg * EE + l + 32] = o1;
    }
  }
}

extern "C" void kernel_launch(void* const* d_in, const int* in_sizes, int n_in,
                              void* d_out, int out_size, void* d_ws, size_t ws_size,
                              hipStream_t stream) {
  const float* x = (const float*)d_in[0];
  const float* w = (const float*)d_in[1];
  const float* b = (const float*)d_in[2];
  float* out_full = (float*)d_out;                 // [T, E] scattered scores
  float* out_idx  = out_full + (size_t)TT * EE;    // [T, K] indices as f32
  if (d_ws && ws_size >= (size_t)(EE * HH * NPL)) {
    char* wgs = (char*)d_ws;
    wdecomp_kernel<<<64, 256, 0, stream>>>(w, wgs);
    router_kernel<true><<<TT / TB, 256, 0, stream>>>(x, w, b, wgs, out_full,
                                                     out_idx);
  } else {
    router_kernel<false><<<TT / TB, 256, 0, stream>>>(x, w, b, nullptr,
                                                      out_full, out_idx);
  }
}